// Round 1
// baseline (108.505 us; speedup 1.0000x reference)
//
#include <hip/hip_runtime.h>
#include <hip/hip_bf16.h>
#include <stdint.h>

#define BB 8
#define TT 2048
#define CC 768
#define HH 64

typedef __bf16 bf16x8 __attribute__((ext_vector_type(8)));
typedef float f32x4 __attribute__((ext_vector_type(4)));

__device__ inline __bf16 f2b(float f) {
    __hip_bfloat16 h = __float2bfloat16(f);
    return __builtin_bit_cast(__bf16, h);
}
__device__ inline ushort f2bits(float f) {
    __hip_bfloat16 h = __float2bfloat16(f);
    return __builtin_bit_cast(ushort, h);
}

// ---------------- Kernel 0: W transpose to bf16 [3][64][768] -------------
// order m: 0=Wq, 1=Wk, 2=Wv
__global__ void wt_kernel(const float* __restrict__ Wk, const float* __restrict__ Wq,
                          const float* __restrict__ Wv, ushort* __restrict__ Wt) {
    int idx = blockIdx.x * 256 + threadIdx.x;
    if (idx >= 3 * 64 * 768) return;
    int m = idx / (64 * 768);
    int r = idx - m * (64 * 768);
    int j = r / 768;       // output col (0..63)
    int c = r - j * 768;   // k index
    const float* W = (m == 0) ? Wq : ((m == 1) ? Wk : Wv);
    Wt[idx] = f2bits(W[(size_t)c * 64 + j]);
}

// ---------------- Kernel 1: QKV projection GEMM --------------------------
// x [B*T][768] fp32, Wt [3][64][768] bf16 -> q,k [B*T][64] bf16, vT [B][64][T] bf16
__launch_bounds__(256)
__global__ void qkv_kernel(const float* __restrict__ x, const ushort* __restrict__ Wt,
                           ushort* __restrict__ qws, ushort* __restrict__ kws,
                           ushort* __restrict__ vws) {
    int wid  = threadIdx.x >> 6;
    int lane = threadIdx.x & 63;
    int m0   = blockIdx.x * 64 + wid * 16;      // wave's row base
    int arow = m0 + (lane & 15);                // A-operand row for this lane
    int koff = (lane >> 4) * 8;

    f32x4 acc[12];
#pragma unroll
    for (int i = 0; i < 12; i++) acc[i] = (f32x4){0.f, 0.f, 0.f, 0.f};

    const float* xrow = x + (size_t)arow * CC;
    for (int kc = 0; kc < CC; kc += 32) {
        const float* xp = xrow + kc + koff;
        float4 x0 = *(const float4*)(xp);
        float4 x1 = *(const float4*)(xp + 4);
        bf16x8 a;
        a[0] = f2b(x0.x); a[1] = f2b(x0.y); a[2] = f2b(x0.z); a[3] = f2b(x0.w);
        a[4] = f2b(x1.x); a[5] = f2b(x1.y); a[6] = f2b(x1.z); a[7] = f2b(x1.w);
#pragma unroll
        for (int nt = 0; nt < 12; nt++) {
            int mm  = nt >> 2;
            int col = (nt & 3) * 16 + (lane & 15);
            const ushort* wp = Wt + ((size_t)mm * 64 + col) * CC + kc + koff;
            bf16x8 bfr = __builtin_bit_cast(bf16x8, *(const uint4*)wp);
            acc[nt] = __builtin_amdgcn_mfma_f32_16x16x32_bf16(a, bfr, acc[nt], 0, 0, 0);
        }
    }

    int r0 = m0 + 4 * (lane >> 4);
    // q (nt 0..3) and k (nt 4..7): C layout row = r0+r, col
#pragma unroll
    for (int nt = 0; nt < 8; nt++) {
        int col = (nt & 3) * 16 + (lane & 15);
        ushort* dst = (nt < 4) ? qws : kws;
#pragma unroll
        for (int r = 0; r < 4; r++)
            dst[(size_t)(r0 + r) * 64 + col] = f2bits(acc[nt][r]);
    }
    // v transposed: vws[b][col][t], 4 consecutive t per lane -> 8B store
    int bidx = r0 >> 11;
    int t0   = r0 & 2047;
#pragma unroll
    for (int j = 0; j < 4; j++) {
        int col = j * 16 + (lane & 15);
        ushort4 pk;
        pk.x = f2bits(acc[8 + j][0]);
        pk.y = f2bits(acc[8 + j][1]);
        pk.z = f2bits(acc[8 + j][2]);
        pk.w = f2bits(acc[8 + j][3]);
        *(ushort4*)&vws[((size_t)bidx * 64 + col) * TT + t0] = pk;
    }
}

// ---------------- Kernel 2: causal flash attention -----------------------
#define QTILE 64
#define KVB 64
#define LDK 72
#define LDV 72
#define LDP 72

__launch_bounds__(256)
__global__ void flash_kernel(const ushort* __restrict__ qg, const ushort* __restrict__ kg,
                             const ushort* __restrict__ vtg, float* __restrict__ out) {
    __shared__ ushort Ks[KVB][LDK];     // K tile [s][h]
    __shared__ ushort Vs[HH][LDV];      // V tile transposed [h][s]
    __shared__ ushort Ps[4][16][LDP];   // per-wave P [q][s]

    int wid  = threadIdx.x >> 6;
    int lane = threadIdx.x & 63;
    int b    = blockIdx.x >> 5;
    int qt   = blockIdx.x & 31;
    int q0   = qt * QTILE;
    int koff = (lane >> 4) * 8;

    // Q fragments (A operand): row = q0 + wid*16 + (lane&15)
    int qrow = q0 + wid * 16 + (lane & 15);
    const ushort* qp = qg + ((size_t)b * TT + qrow) * 64 + koff;
    bf16x8 qf0 = __builtin_bit_cast(bf16x8, *(const uint4*)qp);
    bf16x8 qf1 = __builtin_bit_cast(bf16x8, *(const uint4*)(qp + 32));

    f32x4 o[4];
#pragma unroll
    for (int i = 0; i < 4; i++) o[i] = (f32x4){0.f, 0.f, 0.f, 0.f};
    float mrun[4], lrun[4];
#pragma unroll
    for (int r = 0; r < 4; r++) { mrun[r] = -INFINITY; lrun[r] = 0.f; }

    const float scale = 0.125f;
    int ntiles = qt + 1;   // (q0+QTILE)/KVB

    for (int tile = 0; tile < ntiles; ++tile) {
        int s0 = tile * KVB;
        __syncthreads();   // previous iteration's P/V reads done
        {
            int srow = threadIdx.x >> 2;
            int c0   = (threadIdx.x & 3) * 16;
            const uint4* ksrc = (const uint4*)(kg + ((size_t)b * TT + s0 + srow) * 64 + c0);
            uint4 k0 = ksrc[0], k1 = ksrc[1];
            *(uint4*)&Ks[srow][c0]     = k0;
            *(uint4*)&Ks[srow][c0 + 8] = k1;
            const uint4* vsrc = (const uint4*)(vtg + ((size_t)b * 64 + srow) * TT + s0 + c0);
            uint4 v0 = vsrc[0], v1 = vsrc[1];
            *(uint4*)&Vs[srow][c0]     = v0;
            *(uint4*)&Vs[srow][c0 + 8] = v1;
        }
        __syncthreads();

        // S = Q K^T for 4 n-subtiles
        float sv[4][4];
#pragma unroll
        for (int nt = 0; nt < 4; nt++) {
            const ushort* kp = &Ks[nt * 16 + (lane & 15)][koff];
            bf16x8 kf0 = __builtin_bit_cast(bf16x8, *(const uint4*)kp);
            bf16x8 kf1 = __builtin_bit_cast(bf16x8, *(const uint4*)(kp + 32));
            f32x4 s = (f32x4){0.f, 0.f, 0.f, 0.f};
            s = __builtin_amdgcn_mfma_f32_16x16x32_bf16(qf0, kf0, s, 0, 0, 0);
            s = __builtin_amdgcn_mfma_f32_16x16x32_bf16(qf1, kf1, s, 0, 0, 0);
            int sg = s0 + nt * 16 + (lane & 15);
#pragma unroll
            for (int r = 0; r < 4; r++) {
                int qgl = q0 + wid * 16 + 4 * (lane >> 4) + r;
                float v = s[r] * scale;
                sv[nt][r] = (sg > qgl) ? -INFINITY : v;
            }
        }

        // online softmax (rows split across 16-lane groups)
#pragma unroll
        for (int r = 0; r < 4; r++) {
            float tmax = fmaxf(fmaxf(sv[0][r], sv[1][r]), fmaxf(sv[2][r], sv[3][r]));
#pragma unroll
            for (int off = 1; off < 16; off <<= 1)
                tmax = fmaxf(tmax, __shfl_xor(tmax, off));
            float mnew  = fmaxf(mrun[r], tmax);
            float alpha = __expf(mrun[r] - mnew);
            float psum  = 0.f;
            int prow = 4 * (lane >> 4) + r;
#pragma unroll
            for (int nt = 0; nt < 4; nt++) {
                float p = __expf(sv[nt][r] - mnew);
                psum += p;
                Ps[wid][prow][nt * 16 + (lane & 15)] = f2bits(p);
            }
#pragma unroll
            for (int off = 1; off < 16; off <<= 1)
                psum += __shfl_xor(psum, off);
            lrun[r] = lrun[r] * alpha + psum;
            mrun[r] = mnew;
#pragma unroll
            for (int nth = 0; nth < 4; nth++) o[nth][r] *= alpha;
        }
        __syncthreads();   // P visible; K reads done before next stage

        // O += P V : A = P[16 x 64], B = V[64 x 64] (from Vs transposed)
        bf16x8 pf0 = __builtin_bit_cast(bf16x8, *(const uint4*)&Ps[wid][lane & 15][koff]);
        bf16x8 pf1 = __builtin_bit_cast(bf16x8, *(const uint4*)&Ps[wid][lane & 15][32 + koff]);
#pragma unroll
        for (int nth = 0; nth < 4; nth++) {
            const ushort* vp = &Vs[nth * 16 + (lane & 15)][koff];
            bf16x8 vf0 = __builtin_bit_cast(bf16x8, *(const uint4*)vp);
            bf16x8 vf1 = __builtin_bit_cast(bf16x8, *(const uint4*)(vp + 32));
            o[nth] = __builtin_amdgcn_mfma_f32_16x16x32_bf16(pf0, vf0, o[nth], 0, 0, 0);
            o[nth] = __builtin_amdgcn_mfma_f32_16x16x32_bf16(pf1, vf1, o[nth], 0, 0, 0);
        }
    }

    // epilogue
    float inv[4];
#pragma unroll
    for (int r = 0; r < 4; r++) inv[r] = 1.0f / lrun[r];
#pragma unroll
    for (int nth = 0; nth < 4; nth++) {
#pragma unroll
        for (int r = 0; r < 4; r++) {
            int row = q0 + wid * 16 + 4 * (lane >> 4) + r;
            out[((size_t)b * TT + row) * 64 + nth * 16 + (lane & 15)] = o[nth][r] * inv[r];
        }
    }
}

// ---------------- launch --------------------------------------------------
extern "C" void kernel_launch(void* const* d_in, const int* in_sizes, int n_in,
                              void* d_out, int out_size, void* d_ws, size_t ws_size,
                              hipStream_t stream) {
    const float* x  = (const float*)d_in[0];
    const float* Wk = (const float*)d_in[1];
    const float* Wq = (const float*)d_in[2];
    const float* Wv = (const float*)d_in[3];
    float* out = (float*)d_out;

    ushort* Wt  = (ushort*)d_ws;                            // 3*64*768 = 147456 elems
    ushort* qws = (ushort*)((char*)d_ws + 0x50000);         // [B*T][64]
    ushort* kws = qws + (size_t)BB * TT * 64;
    ushort* vws = kws + (size_t)BB * TT * 64;               // [B][64][T]

    wt_kernel<<<576, 256, 0, stream>>>(Wk, Wq, Wv, Wt);
    qkv_kernel<<<(BB * TT) / 64, 256, 0, stream>>>(x, Wt, qws, kws, vws);
    flash_kernel<<<BB * (TT / QTILE), 256, 0, stream>>>(qws, kws, vws, out);
}

// Round 2
// 102.611 us; speedup vs baseline: 1.0574x; 1.0574x over previous
//
#include <hip/hip_runtime.h>
#include <hip/hip_bf16.h>
#include <stdint.h>

#define BB 8
#define TT 2048
#define CC 768
#define HH 64

typedef __bf16 bf16x8 __attribute__((ext_vector_type(8)));
typedef float f32x4 __attribute__((ext_vector_type(4)));

__device__ inline __bf16 f2b(float f) {
    __hip_bfloat16 h = __float2bfloat16(f);
    return __builtin_bit_cast(__bf16, h);
}
__device__ inline ushort f2bits(float f) {
    __hip_bfloat16 h = __float2bfloat16(f);
    return __builtin_bit_cast(ushort, h);
}

// ---------------- Kernel 0: W transpose to bf16 [3][64][768] -------------
// order m: 0=Wq, 1=Wk, 2=Wv  (flat [192][768], col c = m*64+j)
__global__ void wt_kernel(const float* __restrict__ Wk, const float* __restrict__ Wq,
                          const float* __restrict__ Wv, ushort* __restrict__ Wt) {
    int idx = blockIdx.x * 256 + threadIdx.x;
    if (idx >= 3 * 64 * 768) return;
    int m = idx / (64 * 768);
    int r = idx - m * (64 * 768);
    int j = r / 768;       // output col (0..63)
    int c = r - j * 768;   // k index
    const float* W = (m == 0) ? Wq : ((m == 1) ? Wk : Wv);
    Wt[idx] = f2bits(W[(size_t)c * 64 + j]);
}

// ---------------- Kernel 1: QKV projection GEMM --------------------------
// Block: 16 rows x 192 cols. x-tile staged in LDS (bf16). Wave w owns cols
// [w*48, w*48+48) = 3 MFMA n-tiles. Grid = 16384/16 = 1024 blocks.
#define LDA 40   // 80B row stride: 16B-aligned, 2-way bank aliasing (free)
__launch_bounds__(256)
__global__ void qkv_kernel(const float* __restrict__ x, const ushort* __restrict__ Wt,
                           ushort* __restrict__ qws, ushort* __restrict__ kws,
                           ushort* __restrict__ vws) {
    __shared__ ushort xs[16][LDA];
    int wid  = threadIdx.x >> 6;
    int lane = threadIdx.x & 63;
    int l15  = lane & 15;
    int row0 = blockIdx.x * 16;
    int koff = (lane >> 4) * 8;

    f32x4 acc[3];
#pragma unroll
    for (int i = 0; i < 3; i++) acc[i] = (f32x4){0.f, 0.f, 0.f, 0.f};

    int erow = threadIdx.x >> 4;          // 0..15
    int ecol = (threadIdx.x & 15) * 2;    // 0..30

    for (int kc = 0; kc < CC; kc += 32) {
        __syncthreads();
        float2 xv = *(const float2*)&x[(size_t)(row0 + erow) * CC + kc + ecol];
        xs[erow][ecol]     = f2bits(xv.x);
        xs[erow][ecol + 1] = f2bits(xv.y);
        __syncthreads();
        bf16x8 a = __builtin_bit_cast(bf16x8, *(const uint4*)&xs[l15][koff]);
#pragma unroll
        for (int nt = 0; nt < 3; nt++) {
            int c = wid * 48 + nt * 16 + l15;
            bf16x8 bfr = __builtin_bit_cast(bf16x8, *(const uint4*)&Wt[(size_t)c * CC + kc + koff]);
            acc[nt] = __builtin_amdgcn_mfma_f32_16x16x32_bf16(a, bfr, acc[nt], 0, 0, 0);
        }
    }

    int r0   = row0 + 4 * (lane >> 4);
    int bidx = row0 >> 11;
    int t0   = r0 & 2047;
#pragma unroll
    for (int nt = 0; nt < 3; nt++) {
        int c  = wid * 48 + nt * 16 + l15;
        int mm = c >> 6;
        int j  = c & 63;
        if (mm == 0) {
#pragma unroll
            for (int r = 0; r < 4; r++) qws[(size_t)(r0 + r) * 64 + j] = f2bits(acc[nt][r]);
        } else if (mm == 1) {
#pragma unroll
            for (int r = 0; r < 4; r++) kws[(size_t)(r0 + r) * 64 + j] = f2bits(acc[nt][r]);
        } else {
            ushort4 pk;
            pk.x = f2bits(acc[nt][0]);
            pk.y = f2bits(acc[nt][1]);
            pk.z = f2bits(acc[nt][2]);
            pk.w = f2bits(acc[nt][3]);
            *(ushort4*)&vws[((size_t)bidx * 64 + j) * TT + t0] = pk;
        }
    }
}

// ---------------- Kernel 2: flash attention, wave-task decomposition -----
// Wave-task = (b, 16-row q-tile qt in [0,128), KV segment of 256 rows).
// nseg(qt) = qt/16 + 1; tasks/batch = 576; total 4608; grid 1152 x 256thr.
// No __syncthreads (independent waves). K/V read direct from global (L2).
#define NTPB 576   // tasks per batch
__launch_bounds__(256)
__global__ void flash_kernel(const ushort* __restrict__ qg, const ushort* __restrict__ kg,
                             const ushort* __restrict__ vtg, float* __restrict__ out,
                             float* __restrict__ pO, float* __restrict__ pM,
                             float* __restrict__ pL) {
    __shared__ ushort Ps[4][16][72];   // per-wave P transpose buffer (stride 144B)

    int wid  = threadIdx.x >> 6;
    int lane = threadIdx.x & 63;
    int l15  = lane & 15;
    int hi4  = lane >> 4;
    int koff = hi4 * 8;

    int gw = blockIdx.x * 4 + wid;       // 0..4607
    int b  = gw / NTPB;
    int tp = gw - b * NTPB;
    int g  = 0;
    while (tp >= 8 * (g + 1) * (g + 2)) g++;     // wave-uniform, <=7 iters
    int r_    = tp - 8 * g * (g + 1);
    int qt    = 16 * g + r_ / (g + 1);
    int seg   = r_ - (qt - 16 * g) * (g + 1);
    int nseg  = g + 1;
    int qmin  = qt * 16;
    int s_beg = seg * 256;
    int s_end = s_beg + 256 < qmin + 16 ? s_beg + 256 : qmin + 16;

    const ushort* qp = qg + ((size_t)b * TT + qmin + l15) * 64 + koff;
    bf16x8 qf0 = __builtin_bit_cast(bf16x8, *(const uint4*)qp);
    bf16x8 qf1 = __builtin_bit_cast(bf16x8, *(const uint4*)(qp + 32));

    f32x4 o[4];
#pragma unroll
    for (int i = 0; i < 4; i++) o[i] = (f32x4){0.f, 0.f, 0.f, 0.f};
    float mrun[4], lrun[4];
#pragma unroll
    for (int r = 0; r < 4; r++) { mrun[r] = -INFINITY; lrun[r] = 0.f; }

    const float scale = 0.125f;

    for (int s0 = s_beg; s0 < s_end; s0 += 64) {
        bool maskt = (s0 + 63 > qmin);
        float sv[4][4];
#pragma unroll
        for (int nt = 0; nt < 4; nt++) {
            int krow = s0 + nt * 16 + l15;
            int krl  = krow;
            if (maskt && krl > TT - 1) krl = TT - 1;
            const ushort* kp = kg + ((size_t)b * TT + krl) * 64 + koff;
            bf16x8 kf0 = __builtin_bit_cast(bf16x8, *(const uint4*)kp);
            bf16x8 kf1 = __builtin_bit_cast(bf16x8, *(const uint4*)(kp + 32));
            f32x4 s = (f32x4){0.f, 0.f, 0.f, 0.f};
            s = __builtin_amdgcn_mfma_f32_16x16x32_bf16(qf0, kf0, s, 0, 0, 0);
            s = __builtin_amdgcn_mfma_f32_16x16x32_bf16(qf1, kf1, s, 0, 0, 0);
#pragma unroll
            for (int r = 0; r < 4; r++) {
                float v = s[r] * scale;
                if (maskt) {
                    int qgl = qmin + 4 * hi4 + r;
                    if (krow > qgl) v = -INFINITY;
                }
                sv[nt][r] = v;
            }
        }

        // online softmax (rows split across 16-lane groups)
#pragma unroll
        for (int r = 0; r < 4; r++) {
            float tmax = fmaxf(fmaxf(sv[0][r], sv[1][r]), fmaxf(sv[2][r], sv[3][r]));
#pragma unroll
            for (int off = 1; off < 16; off <<= 1)
                tmax = fmaxf(tmax, __shfl_xor(tmax, off));
            float mnew  = fmaxf(mrun[r], tmax);
            float alpha = __expf(mrun[r] - mnew);
            float psum  = 0.f;
            int prow = 4 * hi4 + r;
#pragma unroll
            for (int nt = 0; nt < 4; nt++) {
                float p = __expf(sv[nt][r] - mnew);
                psum += p;
                Ps[wid][prow][nt * 16 + l15] = f2bits(p);
            }
#pragma unroll
            for (int off = 1; off < 16; off <<= 1)
                psum += __shfl_xor(psum, off);
            lrun[r] = lrun[r] * alpha + psum;
            mrun[r] = mnew;
#pragma unroll
            for (int nth = 0; nth < 4; nth++) o[nth][r] *= alpha;
        }
        // same-wave LDS RAW: compiler inserts lgkmcnt waits; no barrier needed

        bf16x8 pf0 = __builtin_bit_cast(bf16x8, *(const uint4*)&Ps[wid][l15][koff]);
        bf16x8 pf1 = __builtin_bit_cast(bf16x8, *(const uint4*)&Ps[wid][l15][32 + koff]);
#pragma unroll
        for (int nth = 0; nth < 4; nth++) {
            int vh  = nth * 16 + l15;
            int t0v = s0 + koff;
            int t1v = s0 + 32 + koff;
            if (maskt) {
                if (t0v > TT - 8) t0v = TT - 8;
                if (t1v > TT - 8) t1v = TT - 8;
            }
            const ushort* vbase = vtg + ((size_t)b * 64 + vh) * TT;
            bf16x8 vf0 = __builtin_bit_cast(bf16x8, *(const uint4*)(vbase + t0v));
            bf16x8 vf1 = __builtin_bit_cast(bf16x8, *(const uint4*)(vbase + t1v));
            o[nth] = __builtin_amdgcn_mfma_f32_16x16x32_bf16(pf0, vf0, o[nth], 0, 0, 0);
            o[nth] = __builtin_amdgcn_mfma_f32_16x16x32_bf16(pf1, vf1, o[nth], 0, 0, 0);
        }
    }

    if (nseg == 1) {
        float inv[4];
#pragma unroll
        for (int r = 0; r < 4; r++) inv[r] = 1.0f / lrun[r];
#pragma unroll
        for (int nth = 0; nth < 4; nth++)
#pragma unroll
            for (int r = 0; r < 4; r++) {
                int row = qmin + 4 * hi4 + r;
                out[((size_t)b * TT + row) * 64 + nth * 16 + l15] = o[nth][r] * inv[r];
            }
    } else {
        size_t tb = (size_t)(b * NTPB + tp);
#pragma unroll
        for (int nth = 0; nth < 4; nth++)
#pragma unroll
            for (int r = 0; r < 4; r++) {
                int row = 4 * hi4 + r;
                pO[tb * 1024 + row * 64 + nth * 16 + l15] = o[nth][r];
            }
        if (l15 == 0) {
#pragma unroll
            for (int r = 0; r < 4; r++) {
                int row = 4 * hi4 + r;
                pM[tb * 16 + row] = mrun[r];
                pL[tb * 16 + row] = lrun[r];
            }
        }
    }
}

// ---------------- Kernel 3: merge partials for qt >= 16 ------------------
__launch_bounds__(256)
__global__ void merge_kernel(const float* __restrict__ pO, const float* __restrict__ pM,
                             const float* __restrict__ pL, float* __restrict__ out) {
    int b  = blockIdx.x / 112;
    int qt = 16 + (blockIdx.x % 112);
    int g  = qt >> 4;
    int nseg  = g + 1;
    int tbase = b * NTPB + 8 * g * (g + 1) + (qt - 16 * g) * (g + 1);
    int row = threadIdx.x >> 4;
    int col = (threadIdx.x & 15) * 4;

    float mstar = -INFINITY;
    for (int s = 0; s < nseg; s++)
        mstar = fmaxf(mstar, pM[(size_t)(tbase + s) * 16 + row]);
    float4 oa = {0.f, 0.f, 0.f, 0.f};
    float la = 0.f;
    for (int s = 0; s < nseg; s++) {
        float w = __expf(pM[(size_t)(tbase + s) * 16 + row] - mstar);
        la += w * pL[(size_t)(tbase + s) * 16 + row];
        float4 ov = *(const float4*)&pO[(size_t)(tbase + s) * 1024 + row * 64 + col];
        oa.x += w * ov.x; oa.y += w * ov.y; oa.z += w * ov.z; oa.w += w * ov.w;
    }
    float inv = 1.0f / la;
    float4 res = {oa.x * inv, oa.y * inv, oa.z * inv, oa.w * inv};
    *(float4*)&out[((size_t)b * TT + qt * 16 + row) * 64 + col] = res;
}

// ---------------- launch --------------------------------------------------
extern "C" void kernel_launch(void* const* d_in, const int* in_sizes, int n_in,
                              void* d_out, int out_size, void* d_ws, size_t ws_size,
                              hipStream_t stream) {
    const float* x  = (const float*)d_in[0];
    const float* Wk = (const float*)d_in[1];
    const float* Wq = (const float*)d_in[2];
    const float* Wv = (const float*)d_in[3];
    float* out = (float*)d_out;

    char* ws = (char*)d_ws;
    ushort* Wt  = (ushort*)(ws);                 // 294912 B
    ushort* qws = (ushort*)(ws + 0x50000);       // 2 MB  [B*T][64]
    ushort* kws = (ushort*)(ws + 0x250000);      // 2 MB  [B*T][64]
    ushort* vws = (ushort*)(ws + 0x450000);      // 2 MB  [B][64][T]
    float*  pO  = (float*)(ws + 0x650000);       // 4608*1024*4 = 18.9 MB
    float*  pM  = (float*)(ws + 0x1850000);      // 294912 B
    float*  pL  = (float*)(ws + 0x1898000);      // 294912 B

    wt_kernel<<<576, 256, 0, stream>>>(Wk, Wq, Wv, Wt);
    qkv_kernel<<<(BB * TT) / 16, 256, 0, stream>>>(x, Wt, qws, kws, vws);
    flash_kernel<<<(BB * NTPB) / 4, 256, 0, stream>>>(qws, kws, vws, out, pO, pM, pL);
    merge_kernel<<<BB * 112, 256, 0, stream>>>(pO, pM, pL, out);
}

// Round 3
// 84.210 us; speedup vs baseline: 1.2885x; 1.2185x over previous
//
#include <hip/hip_runtime.h>
#include <hip/hip_bf16.h>
#include <stdint.h>

#define BB 8
#define TT 2048
#define CC 768
#define HH 64

typedef __bf16 bf16x8 __attribute__((ext_vector_type(8)));
typedef float f32x4 __attribute__((ext_vector_type(4)));

__device__ inline __bf16 f2b(float f) {
    __hip_bfloat16 h = __float2bfloat16(f);
    return __builtin_bit_cast(__bf16, h);
}
__device__ inline ushort f2bits(float f) {
    __hip_bfloat16 h = __float2bfloat16(f);
    return __builtin_bit_cast(ushort, h);
}

// ---------------- Kernel 0: W transpose to bf16 [3][64][768] -------------
// order m: 0=Wq, 1=Wk, 2=Wv  (flat [192][768], row = m*64+j)
// Block: one 64(c) x 64(j) tile via LDS transpose. Grid = 3*12 = 36.
__launch_bounds__(256)
__global__ void wt_kernel(const float* __restrict__ Wk, const float* __restrict__ Wq,
                          const float* __restrict__ Wv, ushort* __restrict__ Wt) {
    __shared__ float tile[64][65];
    int m  = blockIdx.x / 12;
    int c0 = (blockIdx.x % 12) * 64;
    const float* W = (m == 0) ? Wq : ((m == 1) ? Wk : Wv);
    int tid = threadIdx.x;
#pragma unroll
    for (int i = 0; i < 4; i++) {
        int r   = (tid >> 4) + i * 16;
        int col = (tid & 15) * 4;
        float4 v = *(const float4*)&W[(size_t)(c0 + r) * 64 + col];
        tile[r][col] = v.x; tile[r][col + 1] = v.y;
        tile[r][col + 2] = v.z; tile[r][col + 3] = v.w;
    }
    __syncthreads();
    int j  = tid >> 2;
    int cc = (tid & 3) * 16;
    ushort tmp[16];
#pragma unroll
    for (int e = 0; e < 16; e++) tmp[e] = f2bits(tile[cc + e][j]);
    ushort* dst = &Wt[(size_t)(m * 64 + j) * CC + c0 + cc];
    *(uint4*)(dst)     = *(uint4*)&tmp[0];
    *(uint4*)(dst + 8) = *(uint4*)&tmp[8];
}

// ---------------- Kernel 1: QKV projection GEMM --------------------------
// Block: 32 rows x 192 cols, 4 waves; wave w owns cols [w*48, w*48+48).
// BK=128, double-buffered LDS x-tile (bf16, XOR-swizzled 16B chunks),
// staging split issue-early / write-late. Grid = 16384/32 = 512.
__launch_bounds__(256)
__global__ void qkv_kernel(const float* __restrict__ x, const ushort* __restrict__ Wt,
                           ushort* __restrict__ qws, ushort* __restrict__ kws,
                           ushort* __restrict__ vws) {
    __shared__ ushort xs[2][32][128];   // 8KB per buffer

    int tid  = threadIdx.x;
    int wid  = tid >> 6;
    int lane = tid & 63;
    int l15  = lane & 15;
    int hi4  = lane >> 4;
    int row0 = blockIdx.x * 32;

    // staging mapping: thread -> (srow, 16 consecutive elems at scol)
    int srow = tid >> 3;
    int scol = (tid & 7) * 16;
    int c0   = scol >> 3;       // even 16B-chunk index
    int sw   = srow & 7;        // row swizzle key
    const float* xp = x + (size_t)(row0 + srow) * CC + scol;

    // B pointers (L2-resident Wt)
    const ushort* wtp[3];
#pragma unroll
    for (int nt = 0; nt < 3; nt++)
        wtp[nt] = Wt + (size_t)(wid * 48 + nt * 16 + l15) * CC + hi4 * 8;

    f32x4 acc[2][3];
#pragma unroll
    for (int mm = 0; mm < 2; mm++)
#pragma unroll
        for (int nt = 0; nt < 3; nt++) acc[mm][nt] = (f32x4){0.f, 0.f, 0.f, 0.f};

    float4 p0, p1, p2, p3;   // staged x (issue-early)
    auto ld = [&](int kc) {
        p0 = *(const float4*)(xp + kc);
        p1 = *(const float4*)(xp + kc + 4);
        p2 = *(const float4*)(xp + kc + 8);
        p3 = *(const float4*)(xp + kc + 12);
    };
    auto wr = [&](int buf) {
        ushort lo[8], hi[8];
        lo[0] = f2bits(p0.x); lo[1] = f2bits(p0.y); lo[2] = f2bits(p0.z); lo[3] = f2bits(p0.w);
        lo[4] = f2bits(p1.x); lo[5] = f2bits(p1.y); lo[6] = f2bits(p1.z); lo[7] = f2bits(p1.w);
        hi[0] = f2bits(p2.x); hi[1] = f2bits(p2.y); hi[2] = f2bits(p2.z); hi[3] = f2bits(p2.w);
        hi[4] = f2bits(p3.x); hi[5] = f2bits(p3.y); hi[6] = f2bits(p3.z); hi[7] = f2bits(p3.w);
        *(uint4*)&xs[buf][srow][((c0)     ^ sw) * 8] = *(uint4*)&lo[0];
        *(uint4*)&xs[buf][srow][((c0 + 1) ^ sw) * 8] = *(uint4*)&hi[0];
    };

    ld(0);
    wr(0);
    int cur = 0;
    for (int t = 0; t < 6; t++) {
        __syncthreads();            // buf[cur] visible to all waves
        if (t < 5) ld((t + 1) * 128);   // issue next-chunk loads (hide under compute)
        int kc = t * 128;
#pragma unroll
        for (int ks = 0; ks < 4; ks++) {
            int ch = ((ks * 4 + hi4) ^ (l15 & 7)) * 8;
            bf16x8 a0 = __builtin_bit_cast(bf16x8, *(const uint4*)&xs[cur][l15][ch]);
            bf16x8 a1 = __builtin_bit_cast(bf16x8, *(const uint4*)&xs[cur][16 + l15][ch]);
#pragma unroll
            for (int nt = 0; nt < 3; nt++) {
                bf16x8 b = __builtin_bit_cast(bf16x8, *(const uint4*)(wtp[nt] + kc + ks * 32));
                acc[0][nt] = __builtin_amdgcn_mfma_f32_16x16x32_bf16(a0, b, acc[0][nt], 0, 0, 0);
                acc[1][nt] = __builtin_amdgcn_mfma_f32_16x16x32_bf16(a1, b, acc[1][nt], 0, 0, 0);
            }
        }
        if (t < 5) { wr(cur ^ 1); cur ^= 1; }   // vmcnt wait lands here
    }

    // epilogue: q,k row-major bf16; v transposed [b][h][t]
    int bidx = row0 >> 11;
#pragma unroll
    for (int mm = 0; mm < 2; mm++) {
        int r0 = row0 + mm * 16 + 4 * hi4;
        int t0 = r0 & 2047;
#pragma unroll
        for (int nt = 0; nt < 3; nt++) {
            int c = wid * 48 + nt * 16 + l15;
            int m = c >> 6;
            int j = c & 63;
            if (m == 0) {
#pragma unroll
                for (int r = 0; r < 4; r++)
                    qws[(size_t)(r0 + r) * 64 + j] = f2bits(acc[mm][nt][r]);
            } else if (m == 1) {
#pragma unroll
                for (int r = 0; r < 4; r++)
                    kws[(size_t)(r0 + r) * 64 + j] = f2bits(acc[mm][nt][r]);
            } else {
                ushort4 pk;
                pk.x = f2bits(acc[mm][nt][0]);
                pk.y = f2bits(acc[mm][nt][1]);
                pk.z = f2bits(acc[mm][nt][2]);
                pk.w = f2bits(acc[mm][nt][3]);
                *(ushort4*)&vws[((size_t)bidx * 64 + j) * TT + t0] = pk;
            }
        }
    }
}

// ---------------- Kernel 2: flash attention, wave-task decomposition -----
// Wave-task = (b, 16-row q-tile qt in [0,128), KV segment of 256 rows).
// nseg(qt) = qt/16 + 1; tasks/batch = 576; total 4608; grid 1152 x 256thr.
// No __syncthreads (independent waves). K/V read direct from global (L2).
#define NTPB 576   // tasks per batch
__launch_bounds__(256)
__global__ void flash_kernel(const ushort* __restrict__ qg, const ushort* __restrict__ kg,
                             const ushort* __restrict__ vtg, float* __restrict__ out,
                             float* __restrict__ pO, float* __restrict__ pM,
                             float* __restrict__ pL) {
    __shared__ ushort Ps[4][16][72];   // per-wave P transpose buffer (stride 144B)

    int wid  = threadIdx.x >> 6;
    int lane = threadIdx.x & 63;
    int l15  = lane & 15;
    int hi4  = lane >> 4;
    int koff = hi4 * 8;

    int gw = blockIdx.x * 4 + wid;       // 0..4607
    int b  = gw / NTPB;
    int tp = gw - b * NTPB;
    int g  = 0;
    while (tp >= 8 * (g + 1) * (g + 2)) g++;     // wave-uniform, <=7 iters
    int r_    = tp - 8 * g * (g + 1);
    int qt    = 16 * g + r_ / (g + 1);
    int seg   = r_ - (qt - 16 * g) * (g + 1);
    int nseg  = g + 1;
    int qmin  = qt * 16;
    int s_beg = seg * 256;
    int s_end = s_beg + 256 < qmin + 16 ? s_beg + 256 : qmin + 16;

    const ushort* qp = qg + ((size_t)b * TT + qmin + l15) * 64 + koff;
    bf16x8 qf0 = __builtin_bit_cast(bf16x8, *(const uint4*)qp);
    bf16x8 qf1 = __builtin_bit_cast(bf16x8, *(const uint4*)(qp + 32));

    f32x4 o[4];
#pragma unroll
    for (int i = 0; i < 4; i++) o[i] = (f32x4){0.f, 0.f, 0.f, 0.f};
    float mrun[4], lrun[4];
#pragma unroll
    for (int r = 0; r < 4; r++) { mrun[r] = -INFINITY; lrun[r] = 0.f; }

    const float scale = 0.125f;

    for (int s0 = s_beg; s0 < s_end; s0 += 64) {
        bool maskt = (s0 + 63 > qmin);
        float sv[4][4];
#pragma unroll
        for (int nt = 0; nt < 4; nt++) {
            int krow = s0 + nt * 16 + l15;
            int krl  = krow;
            if (maskt && krl > TT - 1) krl = TT - 1;
            const ushort* kp = kg + ((size_t)b * TT + krl) * 64 + koff;
            bf16x8 kf0 = __builtin_bit_cast(bf16x8, *(const uint4*)kp);
            bf16x8 kf1 = __builtin_bit_cast(bf16x8, *(const uint4*)(kp + 32));
            f32x4 s = (f32x4){0.f, 0.f, 0.f, 0.f};
            s = __builtin_amdgcn_mfma_f32_16x16x32_bf16(qf0, kf0, s, 0, 0, 0);
            s = __builtin_amdgcn_mfma_f32_16x16x32_bf16(qf1, kf1, s, 0, 0, 0);
#pragma unroll
            for (int r = 0; r < 4; r++) {
                float v = s[r] * scale;
                if (maskt) {
                    int qgl = qmin + 4 * hi4 + r;
                    if (krow > qgl) v = -INFINITY;
                }
                sv[nt][r] = v;
            }
        }

        // online softmax (rows split across 16-lane groups)
#pragma unroll
        for (int r = 0; r < 4; r++) {
            float tmax = fmaxf(fmaxf(sv[0][r], sv[1][r]), fmaxf(sv[2][r], sv[3][r]));
#pragma unroll
            for (int off = 1; off < 16; off <<= 1)
                tmax = fmaxf(tmax, __shfl_xor(tmax, off));
            float mnew  = fmaxf(mrun[r], tmax);
            float alpha = __expf(mrun[r] - mnew);
            float psum  = 0.f;
            int prow = 4 * hi4 + r;
#pragma unroll
            for (int nt = 0; nt < 4; nt++) {
                float p = __expf(sv[nt][r] - mnew);
                psum += p;
                Ps[wid][prow][nt * 16 + l15] = f2bits(p);
            }
#pragma unroll
            for (int off = 1; off < 16; off <<= 1)
                psum += __shfl_xor(psum, off);
            lrun[r] = lrun[r] * alpha + psum;
            mrun[r] = mnew;
#pragma unroll
            for (int nth = 0; nth < 4; nth++) o[nth][r] *= alpha;
        }
        // same-wave LDS RAW: compiler inserts lgkmcnt waits; no barrier needed

        bf16x8 pf0 = __builtin_bit_cast(bf16x8, *(const uint4*)&Ps[wid][l15][koff]);
        bf16x8 pf1 = __builtin_bit_cast(bf16x8, *(const uint4*)&Ps[wid][l15][32 + koff]);
#pragma unroll
        for (int nth = 0; nth < 4; nth++) {
            int vh  = nth * 16 + l15;
            int t0v = s0 + koff;
            int t1v = s0 + 32 + koff;
            if (maskt) {
                if (t0v > TT - 8) t0v = TT - 8;
                if (t1v > TT - 8) t1v = TT - 8;
            }
            const ushort* vbase = vtg + ((size_t)b * 64 + vh) * TT;
            bf16x8 vf0 = __builtin_bit_cast(bf16x8, *(const uint4*)(vbase + t0v));
            bf16x8 vf1 = __builtin_bit_cast(bf16x8, *(const uint4*)(vbase + t1v));
            o[nth] = __builtin_amdgcn_mfma_f32_16x16x32_bf16(pf0, vf0, o[nth], 0, 0, 0);
            o[nth] = __builtin_amdgcn_mfma_f32_16x16x32_bf16(pf1, vf1, o[nth], 0, 0, 0);
        }
    }

    if (nseg == 1) {
        float inv[4];
#pragma unroll
        for (int r = 0; r < 4; r++) inv[r] = 1.0f / lrun[r];
#pragma unroll
        for (int nth = 0; nth < 4; nth++)
#pragma unroll
            for (int r = 0; r < 4; r++) {
                int row = qmin + 4 * hi4 + r;
                out[((size_t)b * TT + row) * 64 + nth * 16 + l15] = o[nth][r] * inv[r];
            }
    } else {
        size_t tb = (size_t)(b * NTPB + tp);
#pragma unroll
        for (int nth = 0; nth < 4; nth++)
#pragma unroll
            for (int r = 0; r < 4; r++) {
                int row = 4 * hi4 + r;
                pO[tb * 1024 + row * 64 + nth * 16 + l15] = o[nth][r];
            }
        if (l15 == 0) {
#pragma unroll
            for (int r = 0; r < 4; r++) {
                int row = 4 * hi4 + r;
                pM[tb * 16 + row] = mrun[r];
                pL[tb * 16 + row] = lrun[r];
            }
        }
    }
}

// ---------------- Kernel 3: merge partials for qt >= 16 ------------------
__launch_bounds__(256)
__global__ void merge_kernel(const float* __restrict__ pO, const float* __restrict__ pM,
                             const float* __restrict__ pL, float* __restrict__ out) {
    int b  = blockIdx.x / 112;
    int qt = 16 + (blockIdx.x % 112);
    int g  = qt >> 4;
    int nseg  = g + 1;
    int tbase = b * NTPB + 8 * g * (g + 1) + (qt - 16 * g) * (g + 1);
    int row = threadIdx.x >> 4;
    int col = (threadIdx.x & 15) * 4;

    float mstar = -INFINITY;
    for (int s = 0; s < nseg; s++)
        mstar = fmaxf(mstar, pM[(size_t)(tbase + s) * 16 + row]);
    float4 oa = {0.f, 0.f, 0.f, 0.f};
    float la = 0.f;
    for (int s = 0; s < nseg; s++) {
        float w = __expf(pM[(size_t)(tbase + s) * 16 + row] - mstar);
        la += w * pL[(size_t)(tbase + s) * 16 + row];
        float4 ov = *(const float4*)&pO[(size_t)(tbase + s) * 1024 + row * 64 + col];
        oa.x += w * ov.x; oa.y += w * ov.y; oa.z += w * ov.z; oa.w += w * ov.w;
    }
    float inv = 1.0f / la;
    float4 res = {oa.x * inv, oa.y * inv, oa.z * inv, oa.w * inv};
    *(float4*)&out[((size_t)b * TT + qt * 16 + row) * 64 + col] = res;
}

// ---------------- launch --------------------------------------------------
extern "C" void kernel_launch(void* const* d_in, const int* in_sizes, int n_in,
                              void* d_out, int out_size, void* d_ws, size_t ws_size,
                              hipStream_t stream) {
    const float* x  = (const float*)d_in[0];
    const float* Wk = (const float*)d_in[1];
    const float* Wq = (const float*)d_in[2];
    const float* Wv = (const float*)d_in[3];
    float* out = (float*)d_out;

    char* ws = (char*)d_ws;
    ushort* Wt  = (ushort*)(ws);                 // 294912 B
    ushort* qws = (ushort*)(ws + 0x50000);       // 2 MB  [B*T][64]
    ushort* kws = (ushort*)(ws + 0x250000);      // 2 MB  [B*T][64]
    ushort* vws = (ushort*)(ws + 0x450000);      // 2 MB  [B][64][T]
    float*  pO  = (float*)(ws + 0x650000);       // 4608*1024*4 = 18.9 MB
    float*  pM  = (float*)(ws + 0x1850000);      // 294912 B
    float*  pL  = (float*)(ws + 0x1898000);      // 294912 B

    wt_kernel<<<36, 256, 0, stream>>>(Wk, Wq, Wv, Wt);
    qkv_kernel<<<(BB * TT) / 32, 256, 0, stream>>>(x, Wt, qws, kws, vws);
    flash_kernel<<<(BB * NTPB) / 4, 256, 0, stream>>>(qws, kws, vws, out, pO, pM, pL);
    merge_kernel<<<BB * 112, 256, 0, stream>>>(pO, pM, pL, out);
}